// Round 11
// baseline (55.415 us; speedup 1.0000x reference)
//
#include <hip/hip_runtime.h>
#include <hip/hip_fp16.h>

#define B_  8
#define C_  256
#define H_  64
#define W_  64
#define G_  4
#define CG_ 64
#define K_  9
#define HW_ (H_ * W_)  // 4096

#define WROWS 14
#define WCOLS 32
#define SROW  456   // S_T row stride in halves (16B aligned, +8 pad)

typedef _Float16 f16x8 __attribute__((ext_vector_type(8)));
typedef float    f32x4 __attribute__((ext_vector_type(4)));

// ---------------------------------------------------------------------------
// Deformable sampling as MFMA (deterministic rewrite of r10):
//   out[64ch x 64px] = X[64ch x 448wp] * S[448wp x 64px] per (b,g, 4x16 tile).
//   - S_T[px][wp] fp16, built in LDS by wave 0; lane px owns row px (race-free,
//     order-free). NO atomics anywhere.
//   - Escaped taps (a corner with nonzero weight outside the 14x32 window;
//     ~35 globally) recorded in per-px slots escN/escK; the epilogue
//     recomputes those taps directly from off/msk/x (exact reference math).
//   - A-operand: 32B fp32 global row loads, cast fp16 in-register.
//   - B-operand: ds_read_b128 from S_T (912B stride -> 2-way aliasing, free).
//   - mfma_f32_16x16x32_f16: D[i][j]=sum_k a[i,k]b[j,k]; A row=ch=lane&15,
//     B row=px=lane&15, k-chunk=(lane>>4)*8; D col=lane&15 (px),
//     row=(lane>>4)*4+reg (ch)  [guide-verified; r10 passed first check].
//   - XCD swizzle: per-XCD working set = 4 slabs x 1MB -> ~L2-resident.
//   - Every LDS word read this launch is written this launch. No d_ws.
// ---------------------------------------------------------------------------
struct SM {
  _Float16 S[64][SROW];   // 58368 B
  int      escN[64];      // 256 B
  short    escK[64][8];   // 1024 B
};                        // 59648 B -> 2 blocks/CU

__global__ __launch_bounds__(256, 2) void deform_mfma(const float* __restrict__ x,
                                                      const float* __restrict__ off,
                                                      const float* __restrict__ msk,
                                                      float* __restrict__ out) {
  __shared__ SM sm;

  // XCD-aware swizzle (grid 2048 % 8 == 0): XCD i owns contiguous bg slabs.
  const int orig = blockIdx.x;
  const int wgid = (orig & 7) * 256 + (orig >> 3);
  const int tile = wgid & 63;
  const int bg   = wgid >> 6;
  const int ho0  = (tile >> 2) * 4;   // 16 row-tiles of 4
  const int wo0  = (tile & 3) * 16;   // 4 col-tiles of 16
  const int b    = bg >> 2;
  const int g    = bg & 3;
  const int tid  = threadIdx.x;

  const int wy0 = min(max(ho0 - 5, 0), H_ - WROWS);  // window rows [wy0, +14)
  const int wx0 = min(max(wo0 - 8, 0), W_ - WCOLS);  // window cols [wx0, +32), mult of 8
  const float* slab = x + (size_t)(b * C_ + g * CG_) * HW_;

  // ---- zero S and escN ----
  {
    float4* z = (float4*)sm.S;
    for (int i = tid; i < 3648; i += 256) z[i] = make_float4(0.f, 0.f, 0.f, 0.f);
    if (tid < 64) sm.escN[tid] = 0;
  }
  __syncthreads();

  // ---- S-build: wave 0, lane px owns S row px exclusively ----
  if (tid < 64) {
    const int px = tid;
    const int ho = ho0 + (px >> 4);
    const int wo = wo0 + (px & 15);
    const int pixoff = ho * W_ + wo;

    float dyv[9], dxv[9], mv[9];
#pragma unroll
    for (int k = 0; k < 9; ++k) {
      const size_t obo = (size_t)(b * 72 + (g * 9 + k) * 2) * HW_ + pixoff;
      dyv[k] = off[obo];
      dxv[k] = off[obo + HW_];
      mv[k]  = msk[(size_t)(b * 36 + g * 9 + k) * HW_ + pixoff];
    }

    int en = 0;
#pragma unroll
    for (int k = 0; k < 9; ++k) {
      const int ky = k / 3, kx = k - ky * 3;
      const float py = (float)(ho - 1 + ky) + dyv[k];
      const float qx = (float)(wo - 1 + kx) + dxv[k];
      const float fy = floorf(py), fx = floorf(qx);
      const int y0 = (int)fy, x0 = (int)fx;
      const int y1 = y0 + 1,  x1 = x0 + 1;
      const float ly = py - fy, lx = qx - fx;
      const float m = mv[k];

      const bool vy0 = (unsigned)y0 < (unsigned)H_, vy1 = (unsigned)y1 < (unsigned)H_;
      const bool vx0 = (unsigned)x0 < (unsigned)W_, vx1 = (unsigned)x1 < (unsigned)W_;
      const float w00 = (vy0 && vx0) ? (1.f - ly) * (1.f - lx) * m : 0.f;
      const float w01 = (vy0 && vx1) ? (1.f - ly) * lx * m         : 0.f;
      const float w10 = (vy1 && vx0) ? ly * (1.f - lx) * m         : 0.f;
      const float w11 = (vy1 && vx1) ? ly * lx * m                 : 0.f;

      const int ry0 = y0 - wy0, ry1 = y1 - wy0;
      const int rx0 = x0 - wx0, rx1 = x1 - wx0;
      const bool iy0 = (unsigned)ry0 < WROWS, iy1 = (unsigned)ry1 < WROWS;
      const bool ix0 = (unsigned)rx0 < WCOLS, ix1 = (unsigned)rx1 < WCOLS;
      const bool ok = (w00 == 0.f || (iy0 && ix0)) && (w01 == 0.f || (iy0 && ix1)) &&
                      (w10 == 0.f || (iy1 && ix0)) && (w11 == 0.f || (iy1 && ix1));

      if (ok) {  // zero-weight corners redirected to slot 0 (+0.0: benign)
        const int p00 = (w00 != 0.f) ? ry0 * WCOLS + rx0 : 0;
        const int p01 = (w01 != 0.f) ? ry0 * WCOLS + rx1 : 0;
        const int p10 = (w10 != 0.f) ? ry1 * WCOLS + rx0 : 0;
        const int p11 = (w11 != 0.f) ? ry1 * WCOLS + rx1 : 0;
        sm.S[px][p00] = (_Float16)((float)sm.S[px][p00] + w00);
        sm.S[px][p01] = (_Float16)((float)sm.S[px][p01] + w01);
        sm.S[px][p10] = (_Float16)((float)sm.S[px][p10] + w10);
        sm.S[px][p11] = (_Float16)((float)sm.S[px][p11] + w11);
      } else {   // rare: record tap k for epilogue recompute (no S contribution)
        if (en < 8) sm.escK[px][en] = (short)k;
        ++en;
      }
    }
    sm.escN[px] = min(en, 8);
  }
  __syncthreads();

  // ---- MFMA phase: wave = 16-ch band; 14 k-steps x 4 N-tiles ----
  const int wv   = tid >> 6;          // 0..3
  const int lane = tid & 63;
  const int m0   = wv * 16;           // ch band base
  const int arow = lane & 15;         // A row (ch) / B row (px) within tile
  const int kg8  = (lane >> 4) * 8;   // k-chunk within 32

  f32x4 acc0 = {0.f, 0.f, 0.f, 0.f};
  f32x4 acc1 = {0.f, 0.f, 0.f, 0.f};
  f32x4 acc2 = {0.f, 0.f, 0.f, 0.f};
  f32x4 acc3 = {0.f, 0.f, 0.f, 0.f};

  const float* arowp = slab + (size_t)(m0 + arow) * HW_;

#pragma unroll
  for (int kb = 0; kb < WROWS; ++kb) {
    const float* ap = arowp + (wy0 + kb) * W_ + wx0 + kg8;  // 32B aligned
    const float4 aA = *(const float4*)ap;
    const float4 aB = *(const float4*)(ap + 4);
    f16x8 af;
    af[0] = (_Float16)aA.x; af[1] = (_Float16)aA.y;
    af[2] = (_Float16)aA.z; af[3] = (_Float16)aA.w;
    af[4] = (_Float16)aB.x; af[5] = (_Float16)aB.y;
    af[6] = (_Float16)aB.z; af[7] = (_Float16)aB.w;

    const int kc = kb * WCOLS + kg8;
    const f16x8 bf0 = *(const f16x8*)&sm.S[ 0 + arow][kc];
    const f16x8 bf1 = *(const f16x8*)&sm.S[16 + arow][kc];
    const f16x8 bf2 = *(const f16x8*)&sm.S[32 + arow][kc];
    const f16x8 bf3 = *(const f16x8*)&sm.S[48 + arow][kc];

    acc0 = __builtin_amdgcn_mfma_f32_16x16x32_f16(af, bf0, acc0, 0, 0, 0);
    acc1 = __builtin_amdgcn_mfma_f32_16x16x32_f16(af, bf1, acc1, 0, 0, 0);
    acc2 = __builtin_amdgcn_mfma_f32_16x16x32_f16(af, bf2, acc2, 0, 0, 0);
    acc3 = __builtin_amdgcn_mfma_f32_16x16x32_f16(af, bf3, acc3, 0, 0, 0);
  }

  // ---- epilogue: recompute escaped taps, store (16x4B = 64B segments) ----
  float* ob = out + (size_t)(b * C_ + g * CG_) * HW_;
  const int colx = lane & 15;
  const int rgrp = (lane >> 4) * 4;

#pragma unroll
  for (int nt = 0; nt < 4; ++nt) {
    const f32x4 acc = (nt == 0) ? acc0 : (nt == 1) ? acc1 : (nt == 2) ? acc2 : acc3;
    const int px_ = nt * 16 + colx;     // tile-local pixel (row nt, col colx)
    float c0 = 0.f, c1 = 0.f, c2 = 0.f, c3 = 0.f;

    const int en = sm.escN[px_];
    if (en > 0) {                       // ultra-rare: exact per-tap recompute
      const int ho = ho0 + nt, wo = wo0 + colx;
      const int pixoff = ho * W_ + wo;
      for (int j = 0; j < en; ++j) {
        const int k  = (int)sm.escK[px_][j];
        const int ky = k / 3, kx = k - ky * 3;
        const size_t obo = (size_t)(b * 72 + (g * 9 + k) * 2) * HW_ + pixoff;
        const float dy = off[obo];
        const float dx = off[obo + HW_];
        const float m  = msk[(size_t)(b * 36 + g * 9 + k) * HW_ + pixoff];

        const float py = (float)(ho - 1 + ky) + dy;
        const float qx = (float)(wo - 1 + kx) + dx;
        const float fy = floorf(py), fx = floorf(qx);
        const int y0 = (int)fy, x0 = (int)fx;
        const int y1 = y0 + 1,  x1 = x0 + 1;
        const float ly = py - fy, lx = qx - fx;

        const bool vy0 = (unsigned)y0 < (unsigned)H_, vy1 = (unsigned)y1 < (unsigned)H_;
        const bool vx0 = (unsigned)x0 < (unsigned)W_, vx1 = (unsigned)x1 < (unsigned)W_;
        const float w00 = (vy0 && vx0) ? (1.f - ly) * (1.f - lx) * m : 0.f;
        const float w01 = (vy0 && vx1) ? (1.f - ly) * lx * m         : 0.f;
        const float w10 = (vy1 && vx0) ? ly * (1.f - lx) * m         : 0.f;
        const float w11 = (vy1 && vx1) ? ly * lx * m                 : 0.f;

        const int y0c = min(max(y0, 0), H_ - 1), y1c = min(max(y1, 0), H_ - 1);
        const int x0c = min(max(x0, 0), W_ - 1), x1c = min(max(x1, 0), W_ - 1);
        const int o00 = y0c * W_ + x0c, o01 = y0c * W_ + x1c;
        const int o10 = y1c * W_ + x0c, o11 = y1c * W_ + x1c;

        const float* p0 = slab + (size_t)(m0 + rgrp) * HW_;
        c0 += w00 * p0[o00] + w01 * p0[o01] + w10 * p0[o10] + w11 * p0[o11];
        const float* p1 = p0 + HW_;
        c1 += w00 * p1[o00] + w01 * p1[o01] + w10 * p1[o10] + w11 * p1[o11];
        const float* p2 = p0 + 2 * HW_;
        c2 += w00 * p2[o00] + w01 * p2[o01] + w10 * p2[o10] + w11 * p2[o11];
        const float* p3 = p0 + 3 * HW_;
        c3 += w00 * p3[o00] + w01 * p3[o01] + w10 * p3[o10] + w11 * p3[o11];
      }
    }

    const int gofs = (ho0 + nt) * W_ + wo0 + colx;
    ob[(size_t)(m0 + rgrp + 0) * HW_ + gofs] = acc[0] + c0;
    ob[(size_t)(m0 + rgrp + 1) * HW_ + gofs] = acc[1] + c1;
    ob[(size_t)(m0 + rgrp + 2) * HW_ + gofs] = acc[2] + c2;
    ob[(size_t)(m0 + rgrp + 3) * HW_ + gofs] = acc[3] + c3;
  }
}

// ---------------------------------------------------------------------------
extern "C" void kernel_launch(void* const* d_in, const int* in_sizes, int n_in,
                              void* d_out, int out_size, void* d_ws, size_t ws_size,
                              hipStream_t stream) {
  const float* inp = (const float*)d_in[0];
  const float* off = (const float*)d_in[1];
  const float* msk = (const float*)d_in[2];
  float* out = (float*)d_out;
  (void)d_ws; (void)ws_size;  // unused: single fused kernel, no workspace

  deform_mfma<<<dim3(2048), 256, 0, stream>>>(inp, off, msk, out);
}

// Round 12
// 47.144 us; speedup vs baseline: 1.1754x; 1.1754x over previous
//
#include <hip/hip_runtime.h>
#include <hip/hip_fp16.h>

#define B_  8
#define C_  256
#define H_  64
#define W_  64
#define G_  4
#define CG_ 64
#define HW_ 4096

#define WROWS 12
#define WCOLS 32
#define SROW  392   // 12*32 + 8 pad (halves); stride 196 dw = 4 mod 32 -> 2-way

typedef _Float16 f16x8 __attribute__((ext_vector_type(8)));
typedef float    f32x4 __attribute__((ext_vector_type(4)));

// ---------------------------------------------------------------------------
// K1: NCHW fp32 -> fragment-major fp16  Xt[b][g][y][x/8][ch][x%8]
//   A-fragment waveloads in K2 become 4x256B contiguous segments.
// ---------------------------------------------------------------------------
__global__ __launch_bounds__(256) void to_tiled_f16(const float* __restrict__ in,
                                                    _Float16* __restrict__ out) {
  __shared__ unsigned int tile[64][33];  // [ch][x/2], pad 33 -> ~2-way banks
  const int y = blockIdx.x, g = blockIdx.y, b = blockIdx.z;
  const int tid = threadIdx.x;
  const float* src = in + ((size_t)(b * C_) + g * CG_) * HW_ + y * W_;
  _Float16* dst = out + (size_t)((b * G_ + g) * H_ + y) * (8 * 64 * 8);

  const int ch = tid >> 2;
  const int xh = (tid & 3) * 8;          // u32 (= half2) base within row
  const float* sp = src + (size_t)ch * HW_ + xh * 2;
#pragma unroll
  for (int i = 0; i < 4; ++i) {
    const float4 v = *(const float4*)(sp + i * 4);
    const unsigned u0 = ((unsigned)__half_as_ushort(__float2half(v.y)) << 16) |
                        __half_as_ushort(__float2half(v.x));
    const unsigned u1 = ((unsigned)__half_as_ushort(__float2half(v.w)) << 16) |
                        __half_as_ushort(__float2half(v.z));
    tile[ch][xh + i * 2]     = u0;
    tile[ch][xh + i * 2 + 1] = u1;
  }
  __syncthreads();
#pragma unroll
  for (int rr = 0; rr < 2; ++rr) {
    const int r  = tid + rr * 256;       // run = xc*64 + ch
    const int xc = r >> 6, c2 = r & 63;
    uint4 o;
    o.x = tile[c2][xc * 4 + 0];
    o.y = tile[c2][xc * 4 + 1];
    o.z = tile[c2][xc * 4 + 2];
    o.w = tile[c2][xc * 4 + 3];
    *(uint4*)(dst + (size_t)r * 8) = o;  // 64 lanes x 16B = 1KB contiguous
  }
}

// ---------------------------------------------------------------------------
// K2: deformable sampling as MFMA.
//   out[64ch x 64px] = X[64ch x 384wp] * S[384wp x 64px] per (b,g,4x16 tile).
//   - S_T[px][wp] fp16, built by 64 builders SPREAD ACROSS ALL 4 WAVES
//     (builder iff (tid&3)==0, px = tid>>2; lane-exclusive row -> race-free).
//   - wave wv owns N-tile (px wv*16..+15): B = 1 ds_read_b128/k-step; loops
//     the 4 ch-bands as A (from Xt: 4x256B segments per waveload).
//   - escapes (corner outside 12x32 window, ~0.5/block) -> escN/escK; exact
//     recompute from fp32 x in the epilogue (deterministic, r11-verified).
//   - WROWS=12 -> LDS 51.4KB -> 3 blocks/CU.
// ---------------------------------------------------------------------------
struct SM {
  _Float16 S[64][SROW];   // 50176 B
  int      escN[64];      // 256 B
  short    escK[64][8];   // 1024 B
};                        // 51456 B

__global__ __launch_bounds__(256, 3) void deform_mfma(const float* __restrict__ x,
                                                      const _Float16* __restrict__ xt,
                                                      const float* __restrict__ off,
                                                      const float* __restrict__ msk,
                                                      float* __restrict__ out) {
  __shared__ SM sm;

  const int orig = blockIdx.x;                    // 0..2047; 2048 % 8 == 0
  const int wgid = (orig & 7) * 256 + (orig >> 3);
  const int tile = wgid & 63;
  const int bg   = wgid >> 6;
  const int ho0  = (tile >> 2) * 4;
  const int wo0  = (tile & 3) * 16;
  const int b    = bg >> 2;
  const int g    = bg & 3;
  const int tid  = threadIdx.x;

  const int wy0 = min(max(ho0 - 4, 0), H_ - WROWS);  // rows [wy0, +12)
  const int wx0 = min(max(wo0 - 8, 0), W_ - WCOLS);  // cols [wx0, +32), %8==0
  const float* slab = x + (size_t)(b * C_ + g * CG_) * HW_;

  // ---- zero S ----
  {
    float4* z = (float4*)sm.S;
    for (int i = tid; i < 3136; i += 256) z[i] = make_float4(0.f, 0.f, 0.f, 0.f);
  }
  __syncthreads();

  // ---- S-build: 64 builders spread over all 4 waves ----
  if ((tid & 3) == 0) {
    const int px = tid >> 2;
    const int ho = ho0 + (px >> 4);
    const int wo = wo0 + (px & 15);
    const int pixoff = ho * W_ + wo;

    float dyv[9], dxv[9], mv[9];
#pragma unroll
    for (int k = 0; k < 9; ++k) {
      const size_t obo = (size_t)(b * 72 + (g * 9 + k) * 2) * HW_ + pixoff;
      dyv[k] = off[obo];
      dxv[k] = off[obo + HW_];
      mv[k]  = msk[(size_t)(b * 36 + g * 9 + k) * HW_ + pixoff];
    }

    int en = 0;
#pragma unroll
    for (int k = 0; k < 9; ++k) {
      const int ky = k / 3, kx = k - ky * 3;
      const float py = (float)(ho - 1 + ky) + dyv[k];
      const float qx = (float)(wo - 1 + kx) + dxv[k];
      const float fy = floorf(py), fx = floorf(qx);
      const int y0 = (int)fy, x0 = (int)fx;
      const int y1 = y0 + 1,  x1 = x0 + 1;
      const float ly = py - fy, lx = qx - fx;
      const float m = mv[k];

      const bool vy0 = (unsigned)y0 < (unsigned)H_, vy1 = (unsigned)y1 < (unsigned)H_;
      const bool vx0 = (unsigned)x0 < (unsigned)W_, vx1 = (unsigned)x1 < (unsigned)W_;
      const float w00 = (vy0 && vx0) ? (1.f - ly) * (1.f - lx) * m : 0.f;
      const float w01 = (vy0 && vx1) ? (1.f - ly) * lx * m         : 0.f;
      const float w10 = (vy1 && vx0) ? ly * (1.f - lx) * m         : 0.f;
      const float w11 = (vy1 && vx1) ? ly * lx * m                 : 0.f;

      const int ry0 = y0 - wy0, ry1 = y1 - wy0;
      const int rx0 = x0 - wx0, rx1 = x1 - wx0;
      const bool iy0 = (unsigned)ry0 < WROWS, iy1 = (unsigned)ry1 < WROWS;
      const bool ix0 = (unsigned)rx0 < WCOLS, ix1 = (unsigned)rx1 < WCOLS;
      const bool ok = (w00 == 0.f || (iy0 && ix0)) && (w01 == 0.f || (iy0 && ix1)) &&
                      (w10 == 0.f || (iy1 && ix0)) && (w11 == 0.f || (iy1 && ix1));

      if (ok) {  // zero-weight corners redirect to slot 0 (+0.0 benign)
        const int p00 = (w00 != 0.f) ? ry0 * WCOLS + rx0 : 0;
        const int p01 = (w01 != 0.f) ? ry0 * WCOLS + rx1 : 0;
        const int p10 = (w10 != 0.f) ? ry1 * WCOLS + rx0 : 0;
        const int p11 = (w11 != 0.f) ? ry1 * WCOLS + rx1 : 0;
        sm.S[px][p00] = (_Float16)((float)sm.S[px][p00] + w00);
        sm.S[px][p01] = (_Float16)((float)sm.S[px][p01] + w01);
        sm.S[px][p10] = (_Float16)((float)sm.S[px][p10] + w10);
        sm.S[px][p11] = (_Float16)((float)sm.S[px][p11] + w11);
      } else {
        if (en < 8) sm.escK[px][en] = (short)k;
        ++en;
      }
    }
    sm.escN[px] = min(en, 8);
  }
  __syncthreads();

  // ---- MFMA: wave wv owns px-tile wv; loops 4 ch-bands ----
  const int wv   = tid >> 6;
  const int lane = tid & 63;
  const int arow = lane & 15;
  const int q    = lane >> 4;
  const int prow = wv * 16 + arow;               // S row (px)
  const int xc0  = (wx0 >> 3) + q;               // Xt x-chunk for this lane

  f32x4 acc[4];
#pragma unroll
  for (int mb = 0; mb < 4; ++mb) acc[mb] = (f32x4){0.f, 0.f, 0.f, 0.f};

  const size_t bgh = (size_t)(b * G_ + g) * H_;

#pragma unroll
  for (int kb = 0; kb < WROWS; ++kb) {
    const int y = wy0 + kb;
    const _Float16* xp = xt + (((bgh + y) * 8 + xc0) * 64) * 8 + arow * 8;
    const f16x8 a0 = *(const f16x8*)(xp);
    const f16x8 a1 = *(const f16x8*)(xp + 16 * 8);
    const f16x8 a2 = *(const f16x8*)(xp + 32 * 8);
    const f16x8 a3 = *(const f16x8*)(xp + 48 * 8);
    const f16x8 bf = *(const f16x8*)&sm.S[prow][kb * 32 + q * 8];

    acc[0] = __builtin_amdgcn_mfma_f32_16x16x32_f16(a0, bf, acc[0], 0, 0, 0);
    acc[1] = __builtin_amdgcn_mfma_f32_16x16x32_f16(a1, bf, acc[1], 0, 0, 0);
    acc[2] = __builtin_amdgcn_mfma_f32_16x16x32_f16(a2, bf, acc[2], 0, 0, 0);
    acc[3] = __builtin_amdgcn_mfma_f32_16x16x32_f16(a3, bf, acc[3], 0, 0, 0);
  }

  // ---- epilogue: exact recompute of escaped taps + coalesced stores ----
  float* ob = out + (size_t)(b * C_ + g * CG_) * HW_;
  const int colx = arow;                 // px col within tile
  const int rgrp = q * 4;                // ch sub-row within band
  const int px_  = wv * 16 + colx;
  const int ho   = ho0 + wv;
  const int wo   = wo0 + colx;
  const int gofs = ho * W_ + wo;
  const int en   = sm.escN[px_];

#pragma unroll
  for (int mb = 0; mb < 4; ++mb) {
    float c0 = 0.f, c1 = 0.f, c2 = 0.f, c3 = 0.f;
    if (en > 0) {
      const int pixoff = gofs;
      for (int j = 0; j < en; ++j) {
        const int k  = (int)sm.escK[px_][j];
        const int ky = k / 3, kx = k - ky * 3;
        const size_t obo = (size_t)(b * 72 + (g * 9 + k) * 2) * HW_ + pixoff;
        const float dy = off[obo];
        const float dx = off[obo + HW_];
        const float m  = msk[(size_t)(b * 36 + g * 9 + k) * HW_ + pixoff];

        const float py = (float)(ho - 1 + ky) + dy;
        const float qx = (float)(wo - 1 + kx) + dx;
        const float fy = floorf(py), fx = floorf(qx);
        const int y0 = (int)fy, x0 = (int)fx;
        const int y1 = y0 + 1,  x1 = x0 + 1;
        const float ly = py - fy, lx = qx - fx;

        const bool vy0 = (unsigned)y0 < (unsigned)H_, vy1 = (unsigned)y1 < (unsigned)H_;
        const bool vx0 = (unsigned)x0 < (unsigned)W_, vx1 = (unsigned)x1 < (unsigned)W_;
        const float w00 = (vy0 && vx0) ? (1.f - ly) * (1.f - lx) * m : 0.f;
        const float w01 = (vy0 && vx1) ? (1.f - ly) * lx * m         : 0.f;
        const float w10 = (vy1 && vx0) ? ly * (1.f - lx) * m         : 0.f;
        const float w11 = (vy1 && vx1) ? ly * lx * m                 : 0.f;

        const int y0c = min(max(y0, 0), H_ - 1), y1c = min(max(y1, 0), H_ - 1);
        const int x0c = min(max(x0, 0), W_ - 1), x1c = min(max(x1, 0), W_ - 1);
        const int o00 = y0c * W_ + x0c, o01 = y0c * W_ + x1c;
        const int o10 = y1c * W_ + x0c, o11 = y1c * W_ + x1c;

        const float* p0 = slab + (size_t)(mb * 16 + rgrp) * HW_;
        c0 += w00 * p0[o00] + w01 * p0[o01] + w10 * p0[o10] + w11 * p0[o11];
        const float* p1 = p0 + HW_;
        c1 += w00 * p1[o00] + w01 * p1[o01] + w10 * p1[o10] + w11 * p1[o11];
        const float* p2 = p0 + 2 * HW_;
        c2 += w00 * p2[o00] + w01 * p2[o01] + w10 * p2[o10] + w11 * p2[o11];
        const float* p3 = p0 + 3 * HW_;
        c3 += w00 * p3[o00] + w01 * p3[o01] + w10 * p3[o10] + w11 * p3[o11];
      }
    }
    const int chb = mb * 16 + rgrp;
    ob[(size_t)(chb + 0) * HW_ + gofs] = acc[mb][0] + c0;
    ob[(size_t)(chb + 1) * HW_ + gofs] = acc[mb][1] + c1;
    ob[(size_t)(chb + 2) * HW_ + gofs] = acc[mb][2] + c2;
    ob[(size_t)(chb + 3) * HW_ + gofs] = acc[mb][3] + c3;
  }
}

// ---------------------------------------------------------------------------
// Fallback (no workspace): fp32 NCHW gathers, 4 ch/thread (r1, replay-clean).
// ---------------------------------------------------------------------------
__global__ __launch_bounds__(256) void deform_f32_nchw(const float* __restrict__ x,
                                                       const float* __restrict__ off,
                                                       const float* __restrict__ msk,
                                                       float* __restrict__ out) {
  __shared__ int4   s_o[144];
  __shared__ float4 s_w[144];
  const int woq = blockIdx.x;
  const int ho  = blockIdx.y;
  const int b   = blockIdx.z >> 2;
  const int g   = blockIdx.z & 3;
  const int tid = threadIdx.x;

  if (tid < 144) {
    const int wi = tid / 9, k = tid - wi * 9;
    const int wo = woq * 16 + wi;
    const int ky = k / 3, kx = k - ky * 3;
    const size_t ob = (size_t)(b * 72 + (g * 9 + k) * 2) * HW_ + ho * W_ + wo;
    const float dy = off[ob];
    const float dx = off[ob + HW_];
    const float m  = msk[(size_t)(b * 36 + g * 9 + k) * HW_ + ho * W_ + wo];
    const float py = (float)(ho - 1 + ky) + dy;
    const float px = (float)(wo - 1 + kx) + dx;
    const float fy = floorf(py), fx = floorf(px);
    const int y0 = (int)fy, x0 = (int)fx;
    const int y1 = y0 + 1,  x1 = x0 + 1;
    const float ly = py - fy, lx = px - fx;
    const bool vy0 = (unsigned)y0 < (unsigned)H_, vy1 = (unsigned)y1 < (unsigned)H_;
    const bool vx0 = (unsigned)x0 < (unsigned)W_, vx1 = (unsigned)x1 < (unsigned)W_;
    const float wy0 = (1.f - ly) * m, wy1 = ly * m;
    float4 w;
    w.x = (vy0 && vx0) ? wy0 * (1.f - lx) : 0.f;
    w.y = (vy0 && vx1) ? wy0 * lx         : 0.f;
    w.z = (vy1 && vx0) ? wy1 * (1.f - lx) : 0.f;
    w.w = (vy1 && vx1) ? wy1 * lx         : 0.f;
    const int y0c = min(max(y0, 0), H_ - 1), y1c = min(max(y1, 0), H_ - 1);
    const int x0c = min(max(x0, 0), W_ - 1), x1c = min(max(x1, 0), W_ - 1);
    s_o[tid] = make_int4(y0c * W_ + x0c, y0c * W_ + x1c, y1c * W_ + x0c, y1c * W_ + x1c);
    s_w[tid] = w;
  }
  __syncthreads();

  const int ci = tid & 15, wi = tid >> 4;
  const float* xb = x + (size_t)(b * C_ + g * CG_ + ci * 4) * HW_;
  float a0 = 0.f, a1 = 0.f, a2 = 0.f, a3 = 0.f;
#pragma unroll
  for (int k = 0; k < 9; ++k) {
    const int e = wi * 9 + k;
    const int4   o = s_o[e];
    const float4 w = s_w[e];
    a0 += w.x * xb[o.x] + w.y * xb[o.y] + w.z * xb[o.z] + w.w * xb[o.w];
    const float* x1p = xb + HW_;
    a1 += w.x * x1p[o.x] + w.y * x1p[o.y] + w.z * x1p[o.z] + w.w * x1p[o.w];
    const float* x2p = xb + 2 * HW_;
    a2 += w.x * x2p[o.x] + w.y * x2p[o.y] + w.z * x2p[o.z] + w.w * x2p[o.w];
    const float* x3p = xb + 3 * HW_;
    a3 += w.x * x3p[o.x] + w.y * x3p[o.y] + w.z * x3p[o.z] + w.w * x3p[o.w];
  }
  float* ob = out + (size_t)(b * C_ + g * CG_ + ci * 4) * HW_ + ho * W_ + woq * 16 + wi;
  ob[0] = a0; ob[HW_] = a1; ob[2 * HW_] = a2; ob[3 * HW_] = a3;
}

// ---------------------------------------------------------------------------
extern "C" void kernel_launch(void* const* d_in, const int* in_sizes, int n_in,
                              void* d_out, int out_size, void* d_ws, size_t ws_size,
                              hipStream_t stream) {
  const float* inp = (const float*)d_in[0];
  const float* off = (const float*)d_in[1];
  const float* msk = (const float*)d_in[2];
  float* out = (float*)d_out;

  const size_t need = (size_t)B_ * C_ * HW_ * sizeof(_Float16);  // 16.8 MB
  if (ws_size >= need) {
    _Float16* xt = (_Float16*)d_ws;
    to_tiled_f16<<<dim3(H_, G_, B_), 256, 0, stream>>>(inp, xt);
    deform_mfma<<<dim3(2048), 256, 0, stream>>>(inp, xt, off, msk, out);
  } else {
    deform_f32_nchw<<<dim3(4, H_, B_ * G_), 256, 0, stream>>>(inp, off, msk, out);
  }
}